// Round 3
// baseline (1064.266 us; speedup 1.0000x reference)
//
#include <hip/hip_runtime.h>

// ---------------------------------------------------------------------------
// FullMHA: x(32,512,2048) fp32, w_qkv(6144,2048), w_out(2048,2048)
// qkv = x @ w_qkv^T ; RoPE(64) on q,k ; causal softmax(QK^T/sqrt(128))V ;
// out = y @ w_out^T.  bf16 MFMA 16x16x32 everywhere, fp32 accumulate.
// R3: RoPE + V-transpose hoisted out of attention into one-shot passes;
//     attention stages K/V^T via global_load_lds (swizzled, conflict-free),
//     Q fragments direct-to-register; 3 blocks/CU (42 KB LDS).
// ---------------------------------------------------------------------------

typedef __bf16 bf16x8 __attribute__((ext_vector_type(8)));
typedef float floatx4 __attribute__((ext_vector_type(4)));

__device__ __forceinline__ unsigned short f2bf(float f) {
  union { float f; unsigned u; } v; v.f = f;
  unsigned r = v.u + 0x7FFFu + ((v.u >> 16) & 1u);   // RNE
  return (unsigned short)(r >> 16);
}
__device__ __forceinline__ float bf2f(unsigned short h) {
  union { unsigned u; float f; } v; v.u = ((unsigned)h) << 16; return v.f;
}

__device__ __forceinline__ void load_lds16(const void* g, void* l) {
  __builtin_amdgcn_global_load_lds((__attribute__((address_space(1))) void*)g,
                                   (__attribute__((address_space(3))) void*)l,
                                   16, 0, 0);
}

// ---------------- RoPE tables ----------------------------------------------
__global__ void rope_tables(float* __restrict__ cost, float* __restrict__ sint) {
  int i = blockIdx.x * 256 + threadIdx.x;
  if (i >= 512 * 32) return;
  int t = i >> 5, f = i & 31;
  float e = -(float)(2 * f) / 64.0f;
  float freq = powf(10000.0f, e);
  float ang = (float)t * freq;
  cost[i] = cosf(ang);
  sint[i] = sinf(ang);
}

// ---------------- fp32 -> bf16 cast, 8 elems/thread ------------------------
__global__ void cast_bf16(const float* __restrict__ in,
                          unsigned short* __restrict__ out, int n8) {
  int i = blockIdx.x * 256 + threadIdx.x;
  if (i >= n8) return;
  float4 a = ((const float4*)in)[2 * i];
  float4 b = ((const float4*)in)[2 * i + 1];
  union { uint4 v; unsigned short u[8]; } o;
  o.u[0] = f2bf(a.x); o.u[1] = f2bf(a.y); o.u[2] = f2bf(a.z); o.u[3] = f2bf(a.w);
  o.u[4] = f2bf(b.x); o.u[5] = f2bf(b.y); o.u[6] = f2bf(b.z); o.u[7] = f2bf(b.w);
  ((uint4*)out)[i] = o.v;
}

// ---------------- One-shot RoPE on q,k (in place), Q pre-scaled -------------
// 8 threads per (token,head) row. j<4: rope chunk pair (j, j+4).
// j>=4 (q only): scale pass chunks (j+4, j+8).
__global__ __launch_bounds__(256) void rope_qk(
    unsigned short* __restrict__ qkv, const float* __restrict__ cost,
    const float* __restrict__ sint) {
  const int bid = blockIdx.x;
  const int is_k = bid >= 8192;
  const int gr = (bid & 8191) * 32 + (threadIdx.x >> 3);
  const int j = threadIdx.x & 7;
  const int bt = gr >> 4, h = gr & 15, t = bt & 511;
  unsigned short* p =
      qkv + (size_t)bt * 6144 + h * 128 + (is_k ? 2048 : 0);
  const float qscale = 0.08838834764831845f * 1.4426950408889634f;
  if (j < 4) {
    union { uint4 v; unsigned short u[8]; } a, bb, oa, ob;
    a.v = *(const uint4*)(p + j * 8);
    bb.v = *(const uint4*)(p + j * 8 + 32);
    float4 c0 = *(const float4*)(cost + t * 32 + j * 8);
    float4 c1 = *(const float4*)(cost + t * 32 + j * 8 + 4);
    float4 s0 = *(const float4*)(sint + t * 32 + j * 8);
    float4 s1 = *(const float4*)(sint + t * 32 + j * 8 + 4);
    float cs[8] = {c0.x, c0.y, c0.z, c0.w, c1.x, c1.y, c1.z, c1.w};
    float sn[8] = {s0.x, s0.y, s0.z, s0.w, s1.x, s1.y, s1.z, s1.w};
    const float sc = is_k ? 1.0f : qscale;
#pragma unroll
    for (int jj = 0; jj < 8; ++jj) {
      float x1 = bf2f(a.u[jj]), x2 = bf2f(bb.u[jj]);
      oa.u[jj] = f2bf((x1 * cs[jj] - x2 * sn[jj]) * sc);
      ob.u[jj] = f2bf((x2 * cs[jj] + x1 * sn[jj]) * sc);
    }
    *(uint4*)(p + j * 8) = oa.v;
    *(uint4*)(p + j * 8 + 32) = ob.v;
  } else if (!is_k) {
#pragma unroll
    for (int cc = 0; cc < 2; ++cc) {
      const int chunk = j + 4 + cc * 4;  // chunks 8..15
      union { uint4 v; unsigned short u[8]; } a, oa;
      a.v = *(const uint4*)(p + chunk * 8);
#pragma unroll
      for (int jj = 0; jj < 8; ++jj) oa.u[jj] = f2bf(bf2f(a.u[jj]) * qscale);
      *(uint4*)(p + chunk * 8) = oa.v;
    }
  }
}

// ---------------- One-shot V transpose: vT[bh][d][t] ------------------------
// grid (512 bh, 8 ttile); thread: rowg=tid&7 -> t0=rowg*8, colg=tid>>3 -> d0=colg*4
__global__ __launch_bounds__(256) void transpose_v(
    const unsigned short* __restrict__ qkv, unsigned short* __restrict__ vT) {
  const int bh = blockIdx.x, tt = blockIdx.y;
  const int b = bh >> 4, h = bh & 15;
  const int rowg = threadIdx.x & 7;
  const int colg = threadIdx.x >> 3;
  const int d0 = colg * 4;
  const unsigned short* vbase = qkv +
      (size_t)(b * 512 + tt * 64 + rowg * 8) * 6144 + 4096 + h * 128 + d0;
  uint2 rv[8];
#pragma unroll
  for (int rr = 0; rr < 8; ++rr)
    rv[rr] = *(const uint2*)(vbase + (size_t)rr * 6144);
#pragma unroll
  for (int c = 0; c < 4; ++c) {
    const int d = d0 + c;
    unsigned out[4];
#pragma unroll
    for (int p = 0; p < 4; ++p) {
      unsigned ua = ((const unsigned*)&rv[2 * p])[c >> 1];
      unsigned ub = ((const unsigned*)&rv[2 * p + 1])[c >> 1];
      unsigned lo = (c & 1) ? (ua >> 16) : (ua & 0xffffu);
      unsigned hi = (c & 1) ? (ub >> 16) : (ub & 0xffffu);
      out[p] = lo | (hi << 16);
    }
    *(uint4*)(vT + ((size_t)bh * 128 + d) * 512 + tt * 64 + rowg * 8) =
        *(uint4*)out;
  }
}

// ---------------- GEMM: C[M,N] = A[M,K] * Bt[N,K]^T  (bf16, m97 + swizzle) --
template <int OUT_BF16>
__global__ __launch_bounds__(256) void gemm_bt(
    const unsigned short* __restrict__ A, const unsigned short* __restrict__ Bt,
    void* __restrict__ Cout, int M, int N, int K) {
  __shared__ __align__(16) unsigned short As[128 * 64];
  __shared__ __align__(16) unsigned short Bs[128 * 64];
  const int tid = threadIdx.x;
  const int bn = blockIdx.x, bm = blockIdx.y;
  const int w = tid >> 6, l = tid & 63;
  const int quad = l >> 4, cl = l & 15;
  const int m_base = (w & 1) * 64, n_base = (w >> 1) * 64;
  floatx4 acc[4][4] = {};

  const int srow = tid >> 3;
  const int sc = (tid & 7) ^ (srow & 7);
  const unsigned short* Ag = A + (size_t)(bm * 128 + srow) * K + sc * 8;
  const unsigned short* Bg = Bt + (size_t)(bn * 128 + srow) * K + sc * 8;
  unsigned short* asd = As + tid * 8;
  unsigned short* bsd = Bs + tid * 8;

  for (int kt = 0; kt < K; kt += 64) {
    __syncthreads();
#pragma unroll
    for (int i = 0; i < 4; ++i) {
      load_lds16(Ag + (size_t)i * 32 * K + kt, asd + i * 32 * 64);
      load_lds16(Bg + (size_t)i * 32 * K + kt, bsd + i * 32 * 64);
    }
    __syncthreads();
#pragma unroll
    for (int k0 = 0; k0 < 64; k0 += 32) {
      const int xs = (((k0 >> 3) + quad) ^ (cl & 7)) << 3;
      bf16x8 a[4], b[4];
#pragma unroll
      for (int mt = 0; mt < 4; ++mt)
        a[mt] = *(const bf16x8*)(As + (m_base + mt * 16 + cl) * 64 + xs);
#pragma unroll
      for (int nt = 0; nt < 4; ++nt)
        b[nt] = *(const bf16x8*)(Bs + (n_base + nt * 16 + cl) * 64 + xs);
#pragma unroll
      for (int mt = 0; mt < 4; ++mt)
#pragma unroll
        for (int nt = 0; nt < 4; ++nt)
          acc[mt][nt] = __builtin_amdgcn_mfma_f32_16x16x32_bf16(
              a[mt], b[nt], acc[mt][nt], 0, 0, 0);
    }
  }
#pragma unroll
  for (int mt = 0; mt < 4; ++mt)
#pragma unroll
    for (int nt = 0; nt < 4; ++nt)
#pragma unroll
      for (int r = 0; r < 4; ++r) {
        int gm = bm * 128 + m_base + mt * 16 + quad * 4 + r;
        int gn = bn * 128 + n_base + nt * 16 + cl;
        float v = acc[mt][nt][r];
        if (OUT_BF16)
          ((unsigned short*)Cout)[(size_t)gm * N + gn] = f2bf(v);
        else
          ((float*)Cout)[(size_t)gm * N + gn] = v;
      }
}

// ---------------- Causal flash attention (pre-roped inputs) ----------------
// grid (B*H=512, T/64=8), 4 waves; wave w owns q-rows w*16..+16.
// K / V^T staged via global_load_lds with XOR chunk swizzle; Q frags in regs.
__global__ __launch_bounds__(256) void attn_kernel(
    const unsigned short* __restrict__ qkv, const unsigned short* __restrict__ vT,
    unsigned short* __restrict__ y) {
  __shared__ __align__(16) unsigned short Ks[64 * 128];   // 16 KB, 256B rows
  __shared__ __align__(16) unsigned short VTs[128 * 64];  // 16 KB, 128B rows
  __shared__ __align__(16) unsigned short Ps[4][16][72];  // 9 KB

  const int bh = blockIdx.x, qt = blockIdx.y;
  const int b = bh >> 4, h = bh & 15;
  const int tid = threadIdx.x, w = tid >> 6, l = tid & 63;
  const int quad = l >> 4, cl = l & 15;

  // Q fragments (already roped + scaled) straight from global
  const unsigned short* qrow =
      qkv + (size_t)(b * 512 + qt * 64 + w * 16 + cl) * 6144 + h * 128;
  bf16x8 aq[4];
#pragma unroll
  for (int kc = 0; kc < 4; ++kc)
    aq[kc] = *(const bf16x8*)(qrow + kc * 32 + quad * 8);

  // staging addresses (swizzled chunk fetch, lane-ordered LDS dest)
  const int srK = tid >> 4;                       // 16 rows / inst (256B rows)
  const int scK = (tid & 15) ^ (srK & 7);
  const unsigned short* Kg =
      qkv + (size_t)(b * 512 + srK) * 6144 + 2048 + h * 128 + scK * 8;
  unsigned short* Kd = Ks + tid * 8;
  const int srV = tid >> 3;                       // 32 rows / inst (128B rows)
  const int scV = (tid & 7) ^ (srV & 7);
  const unsigned short* Vg = vT + ((size_t)bh * 128 + srV) * 512 + scV * 8;
  unsigned short* Vd = VTs + tid * 8;

  floatx4 o[8] = {};
  float m_i[4] = {-__builtin_inff(), -__builtin_inff(), -__builtin_inff(),
                  -__builtin_inff()};
  float l_i[4] = {0.f, 0.f, 0.f, 0.f};

  for (int ktile = 0; ktile <= qt; ++ktile) {
    __syncthreads();  // prior PV done reading Ks/VTs
#pragma unroll
    for (int i = 0; i < 4; ++i) {
      load_lds16(Kg + (size_t)(ktile * 64 + i * 16) * 6144, Kd + i * 2048);
      load_lds16(Vg + (size_t)i * 32 * 512 + ktile * 64, Vd + i * 2048);
    }
    __syncthreads();  // staging complete

    // S = Q K^T : wave w -> 16x64 strip
    floatx4 s[4] = {};
#pragma unroll
    for (int kc = 0; kc < 4; ++kc)
#pragma unroll
      for (int nt = 0; nt < 4; ++nt) {
        bf16x8 bk = *(const bf16x8*)(
            Ks + (nt * 16 + cl) * 128 + (((kc * 4 + quad) ^ (cl & 7)) << 3));
        s[nt] = __builtin_amdgcn_mfma_f32_16x16x32_bf16(aq[kc], bk, s[nt],
                                                        0, 0, 0);
      }
    if (ktile == qt) {  // causal mask on diagonal tile
#pragma unroll
      for (int nt = 0; nt < 4; ++nt)
#pragma unroll
        for (int r = 0; r < 4; ++r) {
          int qrow_l = w * 16 + quad * 4 + r;
          int kcol_l = nt * 16 + cl;
          if (kcol_l > qrow_l) s[nt][r] = -__builtin_inff();
        }
    }
    // online softmax (exp2 domain; log2e folded into Q scale)
#pragma unroll
    for (int r = 0; r < 4; ++r) {
      float mx = fmaxf(fmaxf(s[0][r], s[1][r]), fmaxf(s[2][r], s[3][r]));
      mx = fmaxf(mx, __shfl_xor(mx, 1));
      mx = fmaxf(mx, __shfl_xor(mx, 2));
      mx = fmaxf(mx, __shfl_xor(mx, 4));
      mx = fmaxf(mx, __shfl_xor(mx, 8));
      float mn = fmaxf(m_i[r], mx);
      float a = exp2f(m_i[r] - mn);
      float rs = 0.f;
#pragma unroll
      for (int nt = 0; nt < 4; ++nt) {
        float p = exp2f(s[nt][r] - mn);
        s[nt][r] = p;
        rs += p;
      }
      rs += __shfl_xor(rs, 1);
      rs += __shfl_xor(rs, 2);
      rs += __shfl_xor(rs, 4);
      rs += __shfl_xor(rs, 8);
      l_i[r] = l_i[r] * a + rs;
      m_i[r] = mn;
#pragma unroll
      for (int nt2 = 0; nt2 < 8; ++nt2) o[nt2][r] *= a;
#pragma unroll
      for (int nt = 0; nt < 4; ++nt)
        Ps[w][quad * 4 + r][nt * 16 + cl] = f2bf(s[nt][r]);
    }
    __syncthreads();  // P visible (VTs still valid)

    // O += P V
#pragma unroll
    for (int kc2 = 0; kc2 < 2; ++kc2) {
      bf16x8 ap = *(const bf16x8*)(&Ps[w][cl][kc2 * 32 + quad * 8]);
#pragma unroll
      for (int nt2 = 0; nt2 < 8; ++nt2) {
        bf16x8 bv = *(const bf16x8*)(
            VTs + (nt2 * 16 + cl) * 64 + (((kc2 * 4 + quad) ^ (cl & 7)) << 3));
        o[nt2] = __builtin_amdgcn_mfma_f32_16x16x32_bf16(ap, bv, o[nt2],
                                                         0, 0, 0);
      }
    }
  }

  // epilogue: y[bt][h*128+d] = o/l
#pragma unroll
  for (int r = 0; r < 4; ++r) {
    float inv = 1.0f / l_i[r];
    size_t row =
        (size_t)(b * 512 + qt * 64 + w * 16 + quad * 4 + r) * 2048 + h * 128;
#pragma unroll
    for (int nt2 = 0; nt2 < 8; ++nt2)
      y[row + nt2 * 16 + cl] = f2bf(o[nt2][r] * inv);
  }
}

// ---------------------------------------------------------------------------
extern "C" void kernel_launch(void* const* d_in, const int* in_sizes, int n_in,
                              void* d_out, int out_size, void* d_ws,
                              size_t ws_size, hipStream_t stream) {
  const float* x = (const float*)d_in[0];
  const float* wqkv = (const float*)d_in[1];
  const float* wout = (const float*)d_in[2];
  float* out = (float*)d_out;

  char* ws = (char*)d_ws;
  float* cost = (float*)ws;            ws += (size_t)512 * 32 * 4;
  float* sint = (float*)ws;            ws += (size_t)512 * 32 * 4;
  unsigned short* xb = (unsigned short*)ws;    ws += (size_t)16384 * 2048 * 2;
  unsigned short* wqkvb = (unsigned short*)ws; ws += (size_t)6144 * 2048 * 2;
  unsigned short* woutb = (unsigned short*)ws; ws += (size_t)2048 * 2048 * 2;
  unsigned short* qkvb = (unsigned short*)ws;  ws += (size_t)16384 * 6144 * 2;
  unsigned short* yb = (unsigned short*)ws;    ws += (size_t)16384 * 2048 * 2;
  // vT aliases xb (64 MB each): xb is dead after gemm1, vT written after.
  unsigned short* vT = xb;

  rope_tables<<<dim3(64), dim3(256), 0, stream>>>(cost, sint);
  cast_bf16<<<dim3(16384), dim3(256), 0, stream>>>(x, xb, 33554432 / 8);
  cast_bf16<<<dim3(6144), dim3(256), 0, stream>>>(wqkv, wqkvb, 12582912 / 8);
  cast_bf16<<<dim3(2048), dim3(256), 0, stream>>>(wout, woutb, 4194304 / 8);
  gemm_bt<1><<<dim3(48, 128), dim3(256), 0, stream>>>(xb, wqkvb, (void*)qkvb,
                                                      16384, 6144, 2048);
  rope_qk<<<dim3(16384), dim3(256), 0, stream>>>(qkvb, cost, sint);
  transpose_v<<<dim3(512, 8), dim3(256), 0, stream>>>(qkvb, vT);
  attn_kernel<<<dim3(512, 8), dim3(256), 0, stream>>>(qkvb, vT, yb);
  gemm_bt<0><<<dim3(16, 128), dim3(256), 0, stream>>>(yb, woutb, (void*)out,
                                                      16384, 2048, 2048);
}